// Round 6
// baseline (130.592 us; speedup 1.0000x reference)
//
#include <hip/hip_runtime.h>
#include <hip/hip_bf16.h>
#include <stdint.h>

typedef __attribute__((ext_vector_type(4))) float f32x4;
typedef __attribute__((ext_vector_type(4))) unsigned int u32x4;
typedef __attribute__((ext_vector_type(8))) short short8;

#define MFMA16(a, b, c) __builtin_amdgcn_mfma_f32_16x16x32_bf16((a), (b), (c), 0, 0, 0)

__device__ __forceinline__ uint16_t f2bf(float f) {
  __hip_bfloat16 h = __float2bfloat16(f);
  return __builtin_bit_cast(uint16_t, h);
}

// v_rcp_f32-based sigmoid: rcp rel-err ~1ulp << bf16 rounding of every consumer.
__device__ __forceinline__ float fast_sigmoid(float v) {
  return __builtin_amdgcn_rcpf(1.f + __expf(-v));
}

__device__ __forceinline__ short8 cvt8(f32x4 a, f32x4 b) {
  short8 r;
  r[0] = (short)f2bf(a[0]); r[1] = (short)f2bf(a[1]);
  r[2] = (short)f2bf(a[2]); r[3] = (short)f2bf(a[3]);
  r[4] = (short)f2bf(b[0]); r[5] = (short)f2bf(b[1]);
  r[6] = (short)f2bf(b[2]); r[7] = (short)f2bf(b[3]);
  return r;
}

// XOR-swizzled byte offset into row-major [rows][RB bytes] LDS tile (16B slots).
template <int RB>
__device__ __forceinline__ int swzoff(int row, int bcol) {
  constexpr int SLM = (((RB / 16) < 8 ? (RB / 16) : 8)) - 1;
  return row * RB + (bcol ^ ((row & SLM) << 4));
}

// A-fragment (16x32 bf16) from swizzled bf16 LDS tile.
template <int RB>
__device__ __forceinline__ short8 lds_a(const uint16_t* buf, int row0, int k0, int lane) {
  int r = row0 + (lane & 15);
  int bcol = (k0 + ((lane >> 4) << 3)) * 2;
  u32x4 raw = *(const u32x4*)((const char*)buf + swzoff<RB>(r, bcol));
  return __builtin_bit_cast(short8, raw);
}

// A-fragment (16x32 bf16) from the 144B-pitched K=64 staging chunk.
// pitch 144 = 9*16B: bank-group (9r+s)%8 = (r+s)%8 -> 16 rows at fixed slot
// spread evenly over all 8 groups (2 lanes/group = free). No XOR needed.
__device__ __forceinline__ short8 lds_a144(const char* sb, int row0, int kk, int lane) {
  int r = row0 + (lane & 15);
  return *(const short8*)(sb + r * 144 + ((kk * 4 + (lane >> 4)) << 4));
}

// Fragment from row-major fp32 M[ld] (coalesced 16-row pattern)
__device__ __forceinline__ short8 load_frag_f32(const float* M, int ld, int r0, int k0, int lane) {
  const float* p = M + (size_t)(r0 + (lane & 15)) * ld + (k0 + ((lane >> 4) << 3));
  f32x4 a = *(const f32x4*)p;
  f32x4 b = *(const f32x4*)(p + 4);
  return cvt8(a, b);
}

// Packed-path B-fragment: one coalesced 16B load from pre-packed d_ws
__device__ __forceinline__ short8 load_b_pk(const char* base, int f, int lane) {
  u32x4 raw = *(const u32x4*)(base + (((size_t)f * 64 + lane) << 4));
  return __builtin_bit_cast(short8, raw);
}

template <bool P>
__device__ __forceinline__ short8 bfrag(const char* wp, const float* W, int K,
                                        int f0, int ntg, int KT, int kt, int lane) {
  if constexpr (P) {
    return load_b_pk(wp, f0 + ntg * KT + kt, lane);
  } else {
    return load_frag_f32(W, K, ntg * 16, kt * 32, lane);
  }
}

// ---- weight pre-pack: 372 fragments x (64 lanes x 16B) = 372 KB in d_ws ----
__global__ void pack_kernel(const float* __restrict__ w1, const float* __restrict__ w2,
                            const float* __restrict__ w3, const float* __restrict__ w4,
                            const float* __restrict__ w5, char* __restrict__ ws) {
  int b = blockIdx.x, lane = threadIdx.x;
  const float* W;
  int K, f0;
  if (b < 256)      { W = w1; K = 512; f0 = 0; }
  else if (b < 320) { W = w2; K = 256; f0 = 256; }
  else if (b < 336) { W = w3; K = 128; f0 = 320; }
  else if (b < 340) { W = w4; K = 64;  f0 = 336; }
  else              { W = w5; K = 32;  f0 = 340; }
  int f = b - f0;
  int KT = K / 32;
  int nt = f / KT, kt = f % KT;
  short8 r = load_frag_f32(W, K, nt * 16, kt * 32, lane);
  *(u32x4*)(ws + (((size_t)b * 64 + lane) << 4)) = __builtin_bit_cast(u32x4, r);
}

// Non-draining chunk barrier: drain LDS ops only; VMEM prefetches stay in flight.
// sched_barrier(0) fences instruction motion across the barrier (rule #18).
#define CHUNK_BAR()                                           \
  asm volatile("s_waitcnt lgkmcnt(0)" ::: "memory");          \
  __builtin_amdgcn_s_barrier();                               \
  __builtin_amdgcn_sched_barrier(0);

// One L1 K=64 chunk (8 per tile). 32-row tile: each lane stages 8 cols of one
// row (row = wid*8 + lane>>3), one short8 ds_write per chunk. Register-carried
// pipeline; compiler derives all vmcnt waits. (Identical to round-5 KSTEP.)
#define KSTEP64(C)                                                            \
  {                                                                           \
    CHUNK_BAR();                                                              \
    if ((C) + 2 < 8) {                                                        \
      const float* p = xrow + ((C) + 2) * 64;                                 \
      rA[(C) & 1][0] = *(const f32x4*)p;                                      \
      rA[(C) & 1][1] = *(const f32x4*)(p + 4);                                \
    }                                                                         \
    if ((C) + 1 < 8) {                                                        \
      short8 wv = cvt8(rA[((C) + 1) & 1][0], rA[((C) + 1) & 1][1]);           \
      *(short8*)(sring + (((C) + 1) & 1) * 4608 + swb) = wv;                  \
    }                                                                         \
    const char* sc = sring + ((C) & 1) * 4608;                                \
    _Pragma("unroll") for (int m = 0; m < 2; ++m) {                           \
      short8 a = lds_a144(sc, m * 16, 0, lane);                               \
      _Pragma("unroll") for (int nt = 0; nt < 4; ++nt)                        \
          acc[m][nt] = MFMA16(a, bfr[0][nt], acc[m][nt]);                     \
    }                                                                         \
    if (2 * (C) + 2 < 16) {                                                   \
      _Pragma("unroll") for (int nt = 0; nt < 4; ++nt)                        \
          bfr[0][nt] =                                                        \
              bfrag<P>(wp, w1, 512, 0, wid * 4 + nt, 16, 2 * (C) + 2, lane);  \
    }                                                                         \
    _Pragma("unroll") for (int m = 0; m < 2; ++m) {                           \
      short8 a = lds_a144(sc, m * 16, 1, lane);                               \
      _Pragma("unroll") for (int nt = 0; nt < 4; ++nt)                        \
          acc[m][nt] = MFMA16(a, bfr[1][nt], acc[m][nt]);                     \
    }                                                                         \
    if (2 * (C) + 3 < 16) {                                                   \
      _Pragma("unroll") for (int nt = 0; nt < 4; ++nt)                        \
          bfr[1][nt] =                                                        \
              bfrag<P>(wp, w1, 512, 0, wid * 4 + nt, 16, 2 * (C) + 3, lane);  \
    }                                                                         \
  }

// Persistent 2-tile blocks: 1024 blocks x 256 threads, each block runs tiles
// {bb, bb+1024} (32 rows each) back-to-back. Tile 1's chunk-0/1 x-loads are
// issued into the (dead) rA regs during tile 0's last K-steps and fly through
// the whole tail -> tile 1's L1 starts with a hot ring (no cold-start stalls),
// and per-block tail jitter staggers the second half of the kernel (breaks the
// read-burst/write-burst convoy). (256,3): VGPR cap 168 (128-cap spills).
template <bool P>
__global__ __launch_bounds__(256, 3) void mlp5_kernel(
    const float* __restrict__ x,
    const float* __restrict__ w1, const float* __restrict__ b1,
    const float* __restrict__ w2, const float* __restrict__ b2,
    const float* __restrict__ w3, const float* __restrict__ b3,
    const float* __restrict__ w4, const float* __restrict__ b4,
    const float* __restrict__ w5, const float* __restrict__ b5,
    const char* __restrict__ wp, float* __restrict__ out) {
  // Arena 16KB per tile-pass (overlays barrier-protected, as round 5):
  //   L1: S ring [0,9216) = 2 x 4608B bf16 K=64 chunks (144B pitch, reg-staged)
  //   L1 epilogue (after syncthreads): H1 [0,16K) overlays ring
  //   L2: H1 in; H2 [0,8K) out;  L3: H2 in, H3 [8K,12K) out
  //   L4: H3 in, H4 [12K,14K) out;  L5: H4 in
  // Inter-tile ring rewrite of [0,4608) happens after the H4-write barrier,
  // when every wave is past all H1/H2 reads of that region.
  __shared__ __align__(16) char smem[16 * 1024];
  uint16_t* H1 = (uint16_t*)smem;                // [32][256] bf16, RB=512
  uint16_t* H2 = (uint16_t*)smem;                // [32][128] bf16, RB=256
  uint16_t* H3 = (uint16_t*)(smem + 8 * 1024);   // [32][64]  bf16, RB=128
  uint16_t* H4 = (uint16_t*)(smem + 12 * 1024);  // [32][32]  bf16, RB=64

  const int tid = threadIdx.x;
  const int lane = tid & 63;
  const int wid = tid >> 6;
  const int lr = (lane >> 4) << 2;
  const int lc = lane & 15;
  char* sring = smem;

  // in_size = count_nonzero(x[0])
  int in_size = 0;
#pragma unroll
  for (int j = 0; j < 8; ++j) {
    float v = x[j * 64 + lane];
    in_size += (int)__popcll(__ballot(v != 0.f));
  }

  f32x4 acc[2][4];
  f32x4 rA[2][2];
  short8 bfr[2][4];
  const int swb = (wid * 8 + (lane >> 3)) * 144 + ((lane & 7) << 4);

  // ---- tail: L1 epilogue + layers 2..5 for the 32-row tile at row0 ----
  auto tail = [&](f32x4 (&ac)[2][4], int row0) {
    // Hoist L2 weights + L1 bias (latency hides under barrier + epilogue VALU)
    short8 bfr2[2][8];
#pragma unroll
    for (int n = 0; n < 2; ++n)
#pragma unroll
      for (int kt = 0; kt < 8; ++kt)
        bfr2[n][kt] = bfrag<P>(wp, w2, 256, 256, wid * 2 + n, 8, kt, lane);
    float bv1[4];
#pragma unroll
    for (int n = 0; n < 4; ++n) bv1[n] = b1[wid * 64 + n * 16 + lc];

    __syncthreads();  // all S-ring reads done before H1 overlays [0,16K)

    // L1 epilogue: bias + sigmoid -> H1
#pragma unroll
    for (int n = 0; n < 4; ++n) {
      const int ncol = wid * 64 + n * 16;
#pragma unroll
      for (int m = 0; m < 2; ++m)
#pragma unroll
        for (int i = 0; i < 4; ++i) {
          float v = fast_sigmoid(ac[m][n][i] + bv1[n]);
          *(uint16_t*)((char*)H1 + swzoff<512>(m * 16 + lr + i, (ncol + lc) * 2)) = f2bf(v);
        }
    }
    __syncthreads();

    // ---- Layer 2: h1[32x256] -> h2[32x128]
    f32x4 acc2[2][2];
#pragma unroll
    for (int m = 0; m < 2; ++m)
#pragma unroll
      for (int n = 0; n < 2; ++n) acc2[m][n] = (f32x4){0.f, 0.f, 0.f, 0.f};
#pragma unroll
    for (int m = 0; m < 2; ++m) {
#pragma unroll
      for (int kt = 0; kt < 8; ++kt) {
        short8 afr = lds_a<512>(H1, m * 16, kt * 32, lane);
        acc2[m][0] = MFMA16(afr, bfr2[0][kt], acc2[m][0]);
        acc2[m][1] = MFMA16(afr, bfr2[1][kt], acc2[m][1]);
      }
    }
    // Hoist L3 weights + L2 bias
    short8 bfr3[4];
#pragma unroll
    for (int kt = 0; kt < 4; ++kt)
      bfr3[kt] = bfrag<P>(wp, w3, 128, 320, wid, 4, kt, lane);
    float bv2[2];
#pragma unroll
    for (int n = 0; n < 2; ++n) bv2[n] = b2[wid * 32 + n * 16 + lc];
    __syncthreads();  // REQUIRED: last H1 read done before H2 overlays [0,8K)
#pragma unroll
    for (int n = 0; n < 2; ++n) {
      const int ncol = wid * 32 + n * 16;
#pragma unroll
      for (int m = 0; m < 2; ++m)
#pragma unroll
        for (int i = 0; i < 4; ++i) {
          float v = fast_sigmoid(acc2[m][n][i] + bv2[n]);
          *(uint16_t*)((char*)H2 + swzoff<256>(m * 16 + lr + i, (ncol + lc) * 2)) = f2bf(v);
        }
    }
    __syncthreads();

    // ---- Layer 3: h2[32x128] -> h3[32x64]
    f32x4 acc3[2];
#pragma unroll
    for (int m = 0; m < 2; ++m) acc3[m] = (f32x4){0.f, 0.f, 0.f, 0.f};
#pragma unroll
    for (int m = 0; m < 2; ++m)
#pragma unroll
      for (int kt = 0; kt < 4; ++kt) {
        short8 afr = lds_a<256>(H2, m * 16, kt * 32, lane);
        acc3[m] = MFMA16(afr, bfr3[kt], acc3[m]);
      }
    // Hoist L4 weights + L3 bias
    short8 bfr4[2];
#pragma unroll
    for (int kt = 0; kt < 2; ++kt)
      bfr4[kt] = bfrag<P>(wp, w4, 64, 336, wid & 1, 2, kt, lane);
    const float bv3 = b3[wid * 16 + lc];
    // H3 [8K,12K) disjoint from H2 [0,8K): no barrier needed before write
#pragma unroll
    for (int m = 0; m < 2; ++m)
#pragma unroll
      for (int i = 0; i < 4; ++i) {
        float v = fast_sigmoid(acc3[m][i] + bv3);
        *(uint16_t*)((char*)H3 + swzoff<128>(m * 16 + lr + i, (wid * 16 + lc) * 2)) = f2bf(v);
      }
    __syncthreads();

    // ---- Layer 4: h3[32x64] -> h4[32x32]
    const int wm = wid >> 1, wn = wid & 1;
    f32x4 acc4 = (f32x4){0.f, 0.f, 0.f, 0.f};
#pragma unroll
    for (int kt = 0; kt < 2; ++kt) {
      short8 afr = lds_a<128>(H3, wm * 16, kt * 32, lane);
      acc4 = MFMA16(afr, bfr4[kt], acc4);
    }
    // Hoist L5 weights + L4/L5 bias
    short8 bfr5[8];
#pragma unroll
    for (int nt = 0; nt < 8; ++nt)
      bfr5[nt] = bfrag<P>(wp, w5, 32, 340, wid * 8 + nt, 1, 0, lane);
    const float bv4 = b4[wn * 16 + lc];
    float bv5[8];
#pragma unroll
    for (int nt = 0; nt < 8; ++nt) bv5[nt] = b5[wid * 128 + nt * 16 + lc];
    // H4 [12K,14K) disjoint from H3 reads: no barrier needed before write
#pragma unroll
    for (int i = 0; i < 4; ++i) {
      float v = fast_sigmoid(acc4[i] + bv4);
      *(uint16_t*)((char*)H4 + swzoff<64>(wm * 16 + lr + i, (wn * 16 + lc) * 2)) = f2bf(v);
    }
    __syncthreads();

    // ---- Layer 5: h4[32x32] -> out[32x512]
#pragma unroll
    for (int m = 0; m < 2; ++m) {
      short8 afr = lds_a<64>(H4, m * 16, 0, lane);
#pragma unroll
      for (int nt = 0; nt < 8; ++nt) {
        f32x4 av = MFMA16(afr, bfr5[nt], ((f32x4){0.f, 0.f, 0.f, 0.f}));
        const int col = wid * 128 + nt * 16 + lc;
        const bool keep = col < in_size;
#pragma unroll
        for (int i = 0; i < 4; ++i) {
          float v = keep ? (av[i] + bv5[nt]) : 0.f;
          out[(size_t)(row0 + m * 16 + lr + i) * 512 + col] = v;
        }
      }
    }
  };

  // ================= tile 0 =================
  const int row0_0 = blockIdx.x * 32;
  const float* xrow =
      x + (size_t)(row0_0 + wid * 8 + (lane >> 3)) * 512 + ((lane & 7) << 3);
  const float* xrow1 = xrow + (size_t)32768 * 512;  // tile 1's rows (+1024 blocks)

#pragma unroll
  for (int m = 0; m < 2; ++m)
#pragma unroll
    for (int n = 0; n < 4; ++n) acc[m][n] = (f32x4){0.f, 0.f, 0.f, 0.f};

  // Prologue: c0 -> rA[0], c1 -> rA[1]; B(kt0)->bfr[0], B(kt1)->bfr[1];
  // cvt c0 -> ring slot0.
  rA[0][0] = *(const f32x4*)(xrow + 0);
  rA[0][1] = *(const f32x4*)(xrow + 4);
  rA[1][0] = *(const f32x4*)(xrow + 64);
  rA[1][1] = *(const f32x4*)(xrow + 68);
#pragma unroll
  for (int nt = 0; nt < 4; ++nt)
    bfr[0][nt] = bfrag<P>(wp, w1, 512, 0, wid * 4 + nt, 16, 0, lane);
#pragma unroll
  for (int nt = 0; nt < 4; ++nt)
    bfr[1][nt] = bfrag<P>(wp, w1, 512, 0, wid * 4 + nt, 16, 1, lane);
  {
    short8 wv = cvt8(rA[0][0], rA[0][1]);
    *(short8*)(sring + swb) = wv;
  }

  KSTEP64(0) KSTEP64(1) KSTEP64(2) KSTEP64(3)
  KSTEP64(4) KSTEP64(5) KSTEP64(6) KSTEP64(7)

  // Cross-tile handoff: rA is dead after KSTEP(6)'s last write; issue tile 1's
  // chunk-0/1 x-loads now. They stay in flight across the whole tail (~µs),
  // so tile 1's L1 starts hot. (+0 extra VGPR: reuses rA.)
  rA[0][0] = *(const f32x4*)(xrow1 + 0);
  rA[0][1] = *(const f32x4*)(xrow1 + 4);
  rA[1][0] = *(const f32x4*)(xrow1 + 64);
  rA[1][1] = *(const f32x4*)(xrow1 + 68);

  tail(acc, row0_0);

  // ================= tile 1 =================
  // Reload w1 kt0/kt1 fragments (L2-hit; flies under the cvt+write below).
#pragma unroll
  for (int nt = 0; nt < 4; ++nt)
    bfr[0][nt] = bfrag<P>(wp, w1, 512, 0, wid * 4 + nt, 16, 0, lane);
#pragma unroll
  for (int nt = 0; nt < 4; ++nt)
    bfr[1][nt] = bfrag<P>(wp, w1, 512, 0, wid * 4 + nt, 16, 1, lane);
  // Ring slot0 rewrite: safe — every wave passed the H4-write barrier, so all
  // H1/H2 reads of [0,4608) are complete. KSTEP(0)'s CHUNK_BAR publishes it.
  {
    short8 wv = cvt8(rA[0][0], rA[0][1]);
    *(short8*)(sring + swb) = wv;
  }
#pragma unroll
  for (int m = 0; m < 2; ++m)
#pragma unroll
    for (int n = 0; n < 4; ++n) acc[m][n] = (f32x4){0.f, 0.f, 0.f, 0.f};
  xrow = xrow1;

  KSTEP64(0) KSTEP64(1) KSTEP64(2) KSTEP64(3)
  KSTEP64(4) KSTEP64(5) KSTEP64(6) KSTEP64(7)

  tail(acc, row0_0 + 32768);
}

extern "C" void kernel_launch(void* const* d_in, const int* in_sizes, int n_in,
                              void* d_out, int out_size, void* d_ws, size_t ws_size,
                              hipStream_t stream) {
  const float* x  = (const float*)d_in[0];
  const float* w1 = (const float*)d_in[1];
  const float* b1 = (const float*)d_in[2];
  const float* w2 = (const float*)d_in[3];
  const float* b2 = (const float*)d_in[4];
  const float* w3 = (const float*)d_in[5];
  const float* b3 = (const float*)d_in[6];
  const float* w4 = (const float*)d_in[7];
  const float* b4 = (const float*)d_in[8];
  const float* w5 = (const float*)d_in[9];
  const float* b5 = (const float*)d_in[10];
  float* out = (float*)d_out;

  dim3 grid(1024);  // 2 tiles of 32 rows per block
  dim3 block(256);
  const bool packed = ws_size >= (size_t)(372 * 1024);
  if (packed) {
    pack_kernel<<<372, 64, 0, stream>>>(w1, w2, w3, w4, w5, (char*)d_ws);
    mlp5_kernel<true><<<grid, block, 0, stream>>>(x, w1, b1, w2, b2, w3, b3, w4, b4,
                                                  w5, b5, (const char*)d_ws, out);
  } else {
    mlp5_kernel<false><<<grid, block, 0, stream>>>(x, w1, b1, w2, b2, w3, b3, w4, b4,
                                                   w5, b5, nullptr, out);
  }
}

// Round 7
// 111.794 us; speedup vs baseline: 1.1682x; 1.1682x over previous
//
#include <hip/hip_runtime.h>
#include <hip/hip_bf16.h>
#include <stdint.h>

typedef __attribute__((ext_vector_type(4))) float f32x4;
typedef __attribute__((ext_vector_type(4))) unsigned int u32x4;
typedef __attribute__((ext_vector_type(8))) short short8;

#define MFMA16(a, b, c) __builtin_amdgcn_mfma_f32_16x16x32_bf16((a), (b), (c), 0, 0, 0)

__device__ __forceinline__ uint16_t f2bf(float f) {
  __hip_bfloat16 h = __float2bfloat16(f);
  return __builtin_bit_cast(uint16_t, h);
}

// v_rcp_f32-based sigmoid: rcp rel-err ~1ulp << bf16 rounding of every consumer.
__device__ __forceinline__ float fast_sigmoid(float v) {
  return __builtin_amdgcn_rcpf(1.f + __expf(-v));
}

__device__ __forceinline__ short8 cvt8(f32x4 a, f32x4 b) {
  short8 r;
  r[0] = (short)f2bf(a[0]); r[1] = (short)f2bf(a[1]);
  r[2] = (short)f2bf(a[2]); r[3] = (short)f2bf(a[3]);
  r[4] = (short)f2bf(b[0]); r[5] = (short)f2bf(b[1]);
  r[6] = (short)f2bf(b[2]); r[7] = (short)f2bf(b[3]);
  return r;
}

// XOR-swizzled byte offset into row-major [rows][RB bytes] LDS tile (16B slots).
template <int RB>
__device__ __forceinline__ int swzoff(int row, int bcol) {
  constexpr int SLM = (((RB / 16) < 8 ? (RB / 16) : 8)) - 1;
  return row * RB + (bcol ^ ((row & SLM) << 4));
}

// A-fragment (16x32 bf16) from swizzled bf16 LDS tile.
template <int RB>
__device__ __forceinline__ short8 lds_a(const uint16_t* buf, int row0, int k0, int lane) {
  int r = row0 + (lane & 15);
  int bcol = (k0 + ((lane >> 4) << 3)) * 2;
  u32x4 raw = *(const u32x4*)((const char*)buf + swzoff<RB>(r, bcol));
  return __builtin_bit_cast(short8, raw);
}

// A-fragment (16x32 bf16) from an 80B-pitched private 32x32 chunk slab.
// pitch 80 = 5*16B: bank-quad (5r+s)%8 is uniform (8 lanes/quad = b128 floor)
// for both the frag reads (r=lane&15, s=lane>>4) and the staging writes
// (r=lane&31, slots 2h/2h+1). No XOR, no conflicts beyond the b128 minimum.
__device__ __forceinline__ short8 lds_a80(const char* sb, int row0, int lane) {
  int r = row0 + (lane & 15);
  return *(const short8*)(sb + r * 80 + ((lane >> 4) << 4));
}

// Fragment from row-major fp32 M[ld] (coalesced 16-row pattern)
__device__ __forceinline__ short8 load_frag_f32(const float* M, int ld, int r0, int k0, int lane) {
  const float* p = M + (size_t)(r0 + (lane & 15)) * ld + (k0 + ((lane >> 4) << 3));
  f32x4 a = *(const f32x4*)p;
  f32x4 b = *(const f32x4*)(p + 4);
  return cvt8(a, b);
}

// Packed-path B-fragment: one coalesced 16B load from pre-packed d_ws
__device__ __forceinline__ short8 load_b_pk(const char* base, int f, int lane) {
  u32x4 raw = *(const u32x4*)(base + (((size_t)f * 64 + lane) << 4));
  return __builtin_bit_cast(short8, raw);
}

template <bool P>
__device__ __forceinline__ short8 bfrag(const char* wp, const float* W, int K,
                                        int f0, int ntg, int KT, int kt, int lane) {
  if constexpr (P) {
    return load_b_pk(wp, f0 + ntg * KT + kt, lane);
  } else {
    return load_frag_f32(W, K, ntg * 16, kt * 32, lane);
  }
}

// ---- weight pre-pack: 372 fragments x (64 lanes x 16B) = 372 KB in d_ws ----
__global__ void pack_kernel(const float* __restrict__ w1, const float* __restrict__ w2,
                            const float* __restrict__ w3, const float* __restrict__ w4,
                            const float* __restrict__ w5, char* __restrict__ ws) {
  int b = blockIdx.x, lane = threadIdx.x;
  const float* W;
  int K, f0;
  if (b < 256)      { W = w1; K = 512; f0 = 0; }
  else if (b < 320) { W = w2; K = 256; f0 = 256; }
  else if (b < 336) { W = w3; K = 128; f0 = 320; }
  else if (b < 340) { W = w4; K = 64;  f0 = 336; }
  else              { W = w5; K = 32;  f0 = 340; }
  int f = b - f0;
  int KT = K / 32;
  int nt = f / KT, kt = f % KT;
  short8 r = load_frag_f32(W, K, nt * 16, kt * 32, lane);
  *(u32x4*)(ws + (((size_t)b * 64 + lane) << 4)) = __builtin_bit_cast(u32x4, r);
}

// 32 rows/block, 256 threads, 2048 blocks.
// L1 is BARRIER-FREE: each wave privately stages the full 32x32 x-chunk into
// its own 2.5KB LDS slab (producer == consumer => same-wave lgkmcnt ordering
// suffices; no s_barrier until the H1 epilogue). All 16 waves/CU free-run
// through the 512-deep K loop -> the per-chunk 4-wave barrier convoy that
// capped rounds 0-5 at ~76us is structurally removed.
// (256,3): VGPR cap 168 (rounds 1/6 showed tighter caps / more live state
// spill ~50-100MB of scratch HBM traffic).
template <bool P>
__global__ __launch_bounds__(256, 3) void mlp5_kernel(
    const float* __restrict__ x,
    const float* __restrict__ w1, const float* __restrict__ b1,
    const float* __restrict__ w2, const float* __restrict__ b2,
    const float* __restrict__ w3, const float* __restrict__ b3,
    const float* __restrict__ w4, const float* __restrict__ b4,
    const float* __restrict__ w5, const float* __restrict__ b5,
    const char* __restrict__ wp, float* __restrict__ out) {
  // Arena 20KB:
  //   L1: 4 waves x 2 bufs x 2560B private slabs [0,20K)
  //   L1 epilogue (after syncthreads): H1 [0,16K) overlays slabs
  //   L2: H1 in; H2 [0,8K) out (after the barrier following last H1 read)
  //   L3: H2 in, H3 [8K,12K) out
  //   L4: H3 in, H4 [12K,14K) out
  //   L5: H4 in
  __shared__ __align__(16) char smem[20 * 1024];
  uint16_t* H1 = (uint16_t*)smem;                // [32][256] bf16, RB=512
  uint16_t* H2 = (uint16_t*)smem;                // [32][128] bf16, RB=256
  uint16_t* H3 = (uint16_t*)(smem + 8 * 1024);   // [32][64]  bf16, RB=128
  uint16_t* H4 = (uint16_t*)(smem + 12 * 1024);  // [32][32]  bf16, RB=64

  const int tid = threadIdx.x;
  const int lane = tid & 63;
  const int wid = tid >> 6;
  const int row0 = blockIdx.x * 32;
  const int lr = (lane >> 4) << 2;
  const int lc = lane & 15;

  // in_size = count_nonzero(x[0])
  int in_size = 0;
#pragma unroll
  for (int j = 0; j < 8; ++j) {
    float v = x[j * 64 + lane];
    in_size += (int)__popcll(__ballot(v != 0.f));
  }

  // ---- Layer 1: x[32x512] @ w1[256x512]^T -> h1[32x256], barrier-free ----
  // Per wave: acc[2][4] = rows {0-15,16-31} x cols wid*64..+63.
  // Per chunk kt (K=32): lane loads x[row0 + (lane&31)][kt*32 + (lane>>5)*16
  // ..+16) (64B contiguous, rows coalesce across lanes; 4 waves' redundant
  // requests merge in L2/MSHR), cvt once, 2x ds_write_b128 into the private
  // slab, 2x ds_read_b128 frags, 8 MFMA. x-pipeline 3-deep in regs, B frags
  // ping-pong loaded one chunk ahead.
  char* myslab = smem + wid * 5120;  // 2 bufs x 2560B
  const int l31 = lane & 31, lh = lane >> 5;
  const float* xg = x + (size_t)(row0 + l31) * 512 + lh * 16;
  const int wrb = l31 * 80 + lh * 32;

  f32x4 acc[2][4];
#pragma unroll
  for (int m = 0; m < 2; ++m)
#pragma unroll
    for (int n = 0; n < 4; ++n) acc[m][n] = (f32x4){0.f, 0.f, 0.f, 0.f};

  f32x4 xr[3][4];
  short8 bfr[2][4];

  // Prologue: chunks 0,1,2 -> xr[0..2]; B(0)->bfr[0], B(1)->bfr[1];
  // cvt+write chunk0 -> buf0.
#pragma unroll
  for (int c = 0; c < 3; ++c) {
    const float* p = xg + c * 32;
    xr[c][0] = ((const f32x4*)p)[0];
    xr[c][1] = ((const f32x4*)p)[1];
    xr[c][2] = ((const f32x4*)p)[2];
    xr[c][3] = ((const f32x4*)p)[3];
  }
#pragma unroll
  for (int nt = 0; nt < 4; ++nt)
    bfr[0][nt] = bfrag<P>(wp, w1, 512, 0, wid * 4 + nt, 16, 0, lane);
#pragma unroll
  for (int nt = 0; nt < 4; ++nt)
    bfr[1][nt] = bfrag<P>(wp, w1, 512, 0, wid * 4 + nt, 16, 1, lane);
  {
    char* wb = myslab + wrb;
    *(short8*)wb = cvt8(xr[0][0], xr[0][1]);
    *(short8*)(wb + 16) = cvt8(xr[0][2], xr[0][3]);
  }

#pragma unroll
  for (int kt = 0; kt < 16; ++kt) {
    // (1) issue x loads for chunk kt+3 into xr[kt%3] (chunk kt's regs: its
    //     cvt+write happened at iteration kt-1, so they're dead).
    if (kt + 3 < 16) {
      const float* p = xg + (kt + 3) * 32;
      xr[kt % 3][0] = ((const f32x4*)p)[0];
      xr[kt % 3][1] = ((const f32x4*)p)[1];
      xr[kt % 3][2] = ((const f32x4*)p)[2];
      xr[kt % 3][3] = ((const f32x4*)p)[3];
    }
    // (2) cvt + write chunk kt+1 into buf[(kt+1)&1] (that buf's chunk kt-1
    //     frags were read at iteration kt-1; same-wave LDS ordering).
    if (kt + 1 < 16) {
      char* wb = myslab + ((kt + 1) & 1) * 2560 + wrb;
      *(short8*)wb = cvt8(xr[(kt + 1) % 3][0], xr[(kt + 1) % 3][1]);
      *(short8*)(wb + 16) = cvt8(xr[(kt + 1) % 3][2], xr[(kt + 1) % 3][3]);
    }
    // (3) frags + MFMA for chunk kt from buf[kt&1].
    const char* sc = myslab + (kt & 1) * 2560;
    short8 a0 = lds_a80(sc, 0, lane);
    short8 a1 = lds_a80(sc, 16, lane);
#pragma unroll
    for (int nt = 0; nt < 4; ++nt) {
      acc[0][nt] = MFMA16(a0, bfr[kt & 1][nt], acc[0][nt]);
      acc[1][nt] = MFMA16(a1, bfr[kt & 1][nt], acc[1][nt]);
    }
    // (4) reload this slot's B frags for chunk kt+2.
    if (kt + 2 < 16) {
#pragma unroll
      for (int nt = 0; nt < 4; ++nt)
        bfr[kt & 1][nt] = bfrag<P>(wp, w1, 512, 0, wid * 4 + nt, 16, kt + 2, lane);
    }
    // Pin iteration boundaries: prevents full-unroll load hoisting (the
    // r1/r6 spill failure mode). Compile-time only, zero runtime cost.
    __builtin_amdgcn_sched_barrier(0);
  }

  // Hoist L2 weights + L1 bias (latency hides under barrier + epilogue VALU)
  short8 bfr2[2][8];
#pragma unroll
  for (int n = 0; n < 2; ++n)
#pragma unroll
    for (int kt = 0; kt < 8; ++kt)
      bfr2[n][kt] = bfrag<P>(wp, w2, 256, 256, wid * 2 + n, 8, kt, lane);
  float bv1[4];
#pragma unroll
  for (int n = 0; n < 4; ++n) bv1[n] = b1[wid * 64 + n * 16 + lc];

  __syncthreads();  // all private-slab reads done before H1 overlays [0,16K)

  // L1 epilogue: bias + sigmoid -> H1
#pragma unroll
  for (int n = 0; n < 4; ++n) {
    const int ncol = wid * 64 + n * 16;
#pragma unroll
    for (int m = 0; m < 2; ++m)
#pragma unroll
      for (int i = 0; i < 4; ++i) {
        float v = fast_sigmoid(acc[m][n][i] + bv1[n]);
        *(uint16_t*)((char*)H1 + swzoff<512>(m * 16 + lr + i, (ncol + lc) * 2)) = f2bf(v);
      }
  }
  __syncthreads();

  // ---- Layer 2: h1[32x256] -> h2[32x128]; wave cols wid*32 (2 nt), 2 mt, KT=8
  {
    f32x4 acc2[2][2];
#pragma unroll
    for (int m = 0; m < 2; ++m)
#pragma unroll
      for (int n = 0; n < 2; ++n) acc2[m][n] = (f32x4){0.f, 0.f, 0.f, 0.f};
#pragma unroll
    for (int m = 0; m < 2; ++m) {
#pragma unroll
      for (int kt = 0; kt < 8; ++kt) {
        short8 afr = lds_a<512>(H1, m * 16, kt * 32, lane);
        acc2[m][0] = MFMA16(afr, bfr2[0][kt], acc2[m][0]);
        acc2[m][1] = MFMA16(afr, bfr2[1][kt], acc2[m][1]);
      }
    }
    // Hoist L3 weights + L2 bias
    short8 bfr3[4];
#pragma unroll
    for (int kt = 0; kt < 4; ++kt)
      bfr3[kt] = bfrag<P>(wp, w3, 128, 320, wid, 4, kt, lane);
    float bv2[2];
#pragma unroll
    for (int n = 0; n < 2; ++n) bv2[n] = b2[wid * 32 + n * 16 + lc];
    __syncthreads();  // REQUIRED: last H1 read done before H2 overlays [0,8K)
#pragma unroll
    for (int n = 0; n < 2; ++n) {
      const int ncol = wid * 32 + n * 16;
#pragma unroll
      for (int m = 0; m < 2; ++m)
#pragma unroll
        for (int i = 0; i < 4; ++i) {
          float v = fast_sigmoid(acc2[m][n][i] + bv2[n]);
          *(uint16_t*)((char*)H2 + swzoff<256>(m * 16 + lr + i, (ncol + lc) * 2)) = f2bf(v);
        }
    }
    __syncthreads();

    // ---- Layer 3: h2[32x128] -> h3[32x64]; wave col-tile wid (1 nt), 2 mt, KT=4
    f32x4 acc3[2];
#pragma unroll
    for (int m = 0; m < 2; ++m) acc3[m] = (f32x4){0.f, 0.f, 0.f, 0.f};
#pragma unroll
    for (int m = 0; m < 2; ++m)
#pragma unroll
      for (int kt = 0; kt < 4; ++kt) {
        short8 afr = lds_a<256>(H2, m * 16, kt * 32, lane);
        acc3[m] = MFMA16(afr, bfr3[kt], acc3[m]);
      }
    // Hoist L4 weights + L3 bias
    short8 bfr4[2];
#pragma unroll
    for (int kt = 0; kt < 2; ++kt)
      bfr4[kt] = bfrag<P>(wp, w4, 64, 336, wid & 1, 2, kt, lane);
    const float bv3 = b3[wid * 16 + lc];
    // H3 [8K,12K) disjoint from H2 [0,8K): no barrier needed before write
    {
#pragma unroll
      for (int m = 0; m < 2; ++m)
#pragma unroll
        for (int i = 0; i < 4; ++i) {
          float v = fast_sigmoid(acc3[m][i] + bv3);
          *(uint16_t*)((char*)H3 + swzoff<128>(m * 16 + lr + i, (wid * 16 + lc) * 2)) = f2bf(v);
        }
    }
    __syncthreads();

    // ---- Layer 4: h3[32x64] -> h4[32x32]; waves 2x2: rows wm*16 (1 mt), col wn*16, KT=2
    const int wm = wid >> 1, wn = wid & 1;
    f32x4 acc4 = (f32x4){0.f, 0.f, 0.f, 0.f};
#pragma unroll
    for (int kt = 0; kt < 2; ++kt) {
      short8 afr = lds_a<128>(H3, wm * 16, kt * 32, lane);
      acc4 = MFMA16(afr, bfr4[kt], acc4);
    }
    // Hoist L5 weights + L4/L5 bias
    short8 bfr5[8];
#pragma unroll
    for (int nt = 0; nt < 8; ++nt)
      bfr5[nt] = bfrag<P>(wp, w5, 32, 340, wid * 8 + nt, 1, 0, lane);
    const float bv4 = b4[wn * 16 + lc];
    float bv5[8];
#pragma unroll
    for (int nt = 0; nt < 8; ++nt) bv5[nt] = b5[wid * 128 + nt * 16 + lc];
    // H4 [12K,14K) disjoint from H3 reads: no barrier needed before write
    {
#pragma unroll
      for (int i = 0; i < 4; ++i) {
        float v = fast_sigmoid(acc4[i] + bv4);
        *(uint16_t*)((char*)H4 + swzoff<64>(wm * 16 + lr + i, (wn * 16 + lc) * 2)) = f2bf(v);
      }
    }
    __syncthreads();

    // ---- Layer 5: h4[32x32] -> out[32x512]; wave cols wid*128 (8 nt), 2 mt, KT=1
#pragma unroll
    for (int m = 0; m < 2; ++m) {
      short8 afr = lds_a<64>(H4, m * 16, 0, lane);
#pragma unroll
      for (int nt = 0; nt < 8; ++nt) {
        f32x4 av = MFMA16(afr, bfr5[nt], ((f32x4){0.f, 0.f, 0.f, 0.f}));
        const int col = wid * 128 + nt * 16 + lc;
        const bool keep = col < in_size;
#pragma unroll
        for (int i = 0; i < 4; ++i) {
          float v = keep ? (av[i] + bv5[nt]) : 0.f;
          out[(size_t)(row0 + m * 16 + lr + i) * 512 + col] = v;
        }
      }
    }
  }
}

extern "C" void kernel_launch(void* const* d_in, const int* in_sizes, int n_in,
                              void* d_out, int out_size, void* d_ws, size_t ws_size,
                              hipStream_t stream) {
  const float* x  = (const float*)d_in[0];
  const float* w1 = (const float*)d_in[1];
  const float* b1 = (const float*)d_in[2];
  const float* w2 = (const float*)d_in[3];
  const float* b2 = (const float*)d_in[4];
  const float* w3 = (const float*)d_in[5];
  const float* b3 = (const float*)d_in[6];
  const float* w4 = (const float*)d_in[7];
  const float* b4 = (const float*)d_in[8];
  const float* w5 = (const float*)d_in[9];
  const float* b5 = (const float*)d_in[10];
  float* out = (float*)d_out;

  dim3 grid(65536 / 32);
  dim3 block(256);
  const bool packed = ws_size >= (size_t)(372 * 1024);
  if (packed) {
    pack_kernel<<<372, 64, 0, stream>>>(w1, w2, w3, w4, w5, (char*)d_ws);
    mlp5_kernel<true><<<grid, block, 0, stream>>>(x, w1, b1, w2, b2, w3, b3, w4, b4,
                                                  w5, b5, (const char*)d_ws, out);
  } else {
    mlp5_kernel<false><<<grid, block, 0, stream>>>(x, w1, b1, w2, b2, w3, b3, w4, b4,
                                                   w5, b5, nullptr, out);
  }
}

// Round 8
// 109.666 us; speedup vs baseline: 1.1908x; 1.0194x over previous
//
#include <hip/hip_runtime.h>
#include <hip/hip_bf16.h>
#include <stdint.h>

typedef __attribute__((ext_vector_type(4))) float f32x4;
typedef __attribute__((ext_vector_type(4))) unsigned int u32x4;
typedef __attribute__((ext_vector_type(8))) short short8;

#define MFMA16(a, b, c) __builtin_amdgcn_mfma_f32_16x16x32_bf16((a), (b), (c), 0, 0, 0)

__device__ __forceinline__ uint16_t f2bf(float f) {
  __hip_bfloat16 h = __float2bfloat16(f);
  return __builtin_bit_cast(uint16_t, h);
}

// v_rcp_f32-based sigmoid: rcp rel-err ~1ulp << bf16 rounding of every consumer.
__device__ __forceinline__ float fast_sigmoid(float v) {
  return __builtin_amdgcn_rcpf(1.f + __expf(-v));
}

__device__ __forceinline__ short8 cvt8(f32x4 a, f32x4 b) {
  short8 r;
  r[0] = (short)f2bf(a[0]); r[1] = (short)f2bf(a[1]);
  r[2] = (short)f2bf(a[2]); r[3] = (short)f2bf(a[3]);
  r[4] = (short)f2bf(b[0]); r[5] = (short)f2bf(b[1]);
  r[6] = (short)f2bf(b[2]); r[7] = (short)f2bf(b[3]);
  return r;
}

// XOR-swizzled byte offset into row-major [rows][RB bytes] LDS tile (16B slots).
template <int RB>
__device__ __forceinline__ int swzoff(int row, int bcol) {
  constexpr int SLM = (((RB / 16) < 8 ? (RB / 16) : 8)) - 1;
  return row * RB + (bcol ^ ((row & SLM) << 4));
}

// A-fragment (16x32 bf16) from swizzled bf16 LDS tile.
template <int RB>
__device__ __forceinline__ short8 lds_a(const uint16_t* buf, int row0, int k0, int lane) {
  int r = row0 + (lane & 15);
  int bcol = (k0 + ((lane >> 4) << 3)) * 2;
  u32x4 raw = *(const u32x4*)((const char*)buf + swzoff<RB>(r, bcol));
  return __builtin_bit_cast(short8, raw);
}

// Fragment from row-major fp32 M[ld] (coalesced 16-row pattern)
__device__ __forceinline__ short8 load_frag_f32(const float* M, int ld, int r0, int k0, int lane) {
  const float* p = M + (size_t)(r0 + (lane & 15)) * ld + (k0 + ((lane >> 4) << 3));
  f32x4 a = *(const f32x4*)p;
  f32x4 b = *(const f32x4*)(p + 4);
  return cvt8(a, b);
}

// Packed-path B-fragment: one coalesced 16B load from pre-packed d_ws
__device__ __forceinline__ short8 load_b_pk(const char* base, int f, int lane) {
  u32x4 raw = *(const u32x4*)(base + (((size_t)f * 64 + lane) << 4));
  return __builtin_bit_cast(short8, raw);
}

template <bool P>
__device__ __forceinline__ short8 bfrag(const char* wp, const float* W, int K,
                                        int f0, int ntg, int KT, int kt, int lane) {
  if constexpr (P) {
    return load_b_pk(wp, f0 + ntg * KT + kt, lane);
  } else {
    return load_frag_f32(W, K, ntg * 16, kt * 32, lane);
  }
}

// ---- weight pre-pack: 372 fragments x (64 lanes x 16B) = 372 KB in d_ws ----
__global__ void pack_kernel(const float* __restrict__ w1, const float* __restrict__ w2,
                            const float* __restrict__ w3, const float* __restrict__ w4,
                            const float* __restrict__ w5, char* __restrict__ ws) {
  int b = blockIdx.x, lane = threadIdx.x;
  const float* W;
  int K, f0;
  if (b < 256)      { W = w1; K = 512; f0 = 0; }
  else if (b < 320) { W = w2; K = 256; f0 = 256; }
  else if (b < 336) { W = w3; K = 128; f0 = 320; }
  else if (b < 340) { W = w4; K = 64;  f0 = 336; }
  else              { W = w5; K = 32;  f0 = 340; }
  int f = b - f0;
  int KT = K / 32;
  int nt = f / KT, kt = f % KT;
  short8 r = load_frag_f32(W, K, nt * 16, kt * 32, lane);
  *(u32x4*)(ws + (((size_t)b * 64 + lane) << 4)) = __builtin_bit_cast(u32x4, r);
}

// 32 rows/block, 256 threads, 2048 blocks.
// L1 has NO LDS AND NO BARRIERS: the MFMA A-fragment (row=lane&15,
// k=(lane>>4)*8..+8) is loaded straight from row-major x global->reg (128B
// contiguous per row; the 4 waves' redundant reads are served by per-CU L1$).
// This removes r7's same-wave ds_write->ds_read round-trip (the +40us
// serializer) AND rounds 0-5's per-chunk 4-wave barrier convoy. x raw loads
// run 3 chunks ahead (rotating 48-VGPR buffer), cvt 1 chunk ahead, B frags
// ping-pong 2 ahead. (256,3): VGPR cap 168 (r1/r6: tighter caps or more live
// state spill 50-100MB of scratch to HBM; guard = WRITE_SIZE staying ~131MB).
template <bool P>
__global__ __launch_bounds__(256, 3) void mlp5_kernel(
    const float* __restrict__ x,
    const float* __restrict__ w1, const float* __restrict__ b1,
    const float* __restrict__ w2, const float* __restrict__ b2,
    const float* __restrict__ w3, const float* __restrict__ b3,
    const float* __restrict__ w4, const float* __restrict__ b4,
    const float* __restrict__ w5, const float* __restrict__ b5,
    const char* __restrict__ wp, float* __restrict__ out) {
  // Arena 16KB (every overlay barrier-protected, as round 5):
  //   H1 [0,16K) (written fresh after L1; no staging to protect)
  //   L2: H1 in; H2 [0,8K) out (after the barrier following last H1 read)
  //   L3: H2 in, H3 [8K,12K) out
  //   L4: H3 in, H4 [12K,14K) out
  //   L5: H4 in
  __shared__ __align__(16) char smem[16 * 1024];
  uint16_t* H1 = (uint16_t*)smem;                // [32][256] bf16, RB=512
  uint16_t* H2 = (uint16_t*)smem;                // [32][128] bf16, RB=256
  uint16_t* H3 = (uint16_t*)(smem + 8 * 1024);   // [32][64]  bf16, RB=128
  uint16_t* H4 = (uint16_t*)(smem + 12 * 1024);  // [32][32]  bf16, RB=64

  const int tid = threadIdx.x;
  const int lane = tid & 63;
  const int wid = tid >> 6;
  const int row0 = blockIdx.x * 32;
  const int lr = (lane >> 4) << 2;
  const int lc = lane & 15;

  // in_size = count_nonzero(x[0])
  int in_size = 0;
#pragma unroll
  for (int j = 0; j < 8; ++j) {
    float v = x[j * 64 + lane];
    in_size += (int)__popcll(__ballot(v != 0.f));
  }

  // ---- Layer 1: x[32x512] @ w1[256x512]^T -> h1[32x256], LDS-free ----
  // Wave w: acc[2][4] = rows {0-15,16-31} x cols w*64..+63.
  // Per chunk kt: 2 A-frags direct from global (4x f32x4, 128B/row), cvt once,
  // 4 packed B-frags, 8 MFMA. Pipeline: raw loads kt+3, cvt kt+1, MFMA kt.
  const float* xa = x + (size_t)(row0 + (lane & 15)) * 512 + ((lane >> 4) << 3);

  f32x4 acc[2][4];
#pragma unroll
  for (int m = 0; m < 2; ++m)
#pragma unroll
    for (int n = 0; n < 4; ++n) acc[m][n] = (f32x4){0.f, 0.f, 0.f, 0.f};

  f32x4 xraw[3][2][2];  // [slot][m][half]
  short8 afr[2][2];     // [slot][m]
  short8 bfr[2][4];

  // Prologue: raw chunks 0,1,2 -> slots 0,1,2; B(0)->bfr[0], B(1)->bfr[1];
  // cvt chunk0 -> afr[0] (compiler waits only chunk0's loads).
#pragma unroll
  for (int c = 0; c < 3; ++c) {
#pragma unroll
    for (int m = 0; m < 2; ++m) {
      const float* p = xa + (size_t)m * (16 * 512) + c * 32;
      xraw[c][m][0] = *(const f32x4*)p;
      xraw[c][m][1] = *(const f32x4*)(p + 4);
    }
  }
#pragma unroll
  for (int nt = 0; nt < 4; ++nt)
    bfr[0][nt] = bfrag<P>(wp, w1, 512, 0, wid * 4 + nt, 16, 0, lane);
#pragma unroll
  for (int nt = 0; nt < 4; ++nt)
    bfr[1][nt] = bfrag<P>(wp, w1, 512, 0, wid * 4 + nt, 16, 1, lane);
#pragma unroll
  for (int m = 0; m < 2; ++m)
    afr[0][m] = cvt8(xraw[0][m][0], xraw[0][m][1]);

#pragma unroll
  for (int kt = 0; kt < 16; ++kt) {
    // (1) raw loads for chunk kt+3 into slot kt%3 (its chunk-kt data was
    //     cvt'd at iteration kt-1 -> regs dead).
    if (kt + 3 < 16) {
#pragma unroll
      for (int m = 0; m < 2; ++m) {
        const float* p = xa + (size_t)m * (16 * 512) + (kt + 3) * 32;
        xraw[kt % 3][m][0] = *(const f32x4*)p;
        xraw[kt % 3][m][1] = *(const f32x4*)(p + 4);
      }
    }
    // (2) MFMA chunk kt (frags + B already in regs; no waits on this path).
#pragma unroll
    for (int nt = 0; nt < 4; ++nt) {
      acc[0][nt] = MFMA16(afr[kt & 1][0], bfr[kt & 1][nt], acc[0][nt]);
      acc[1][nt] = MFMA16(afr[kt & 1][1], bfr[kt & 1][nt], acc[1][nt]);
    }
    // (3) cvt chunk kt+1 (raw loaded at iteration kt-2; 2-iter lead covers
    //     L1$/L2 latency).
    if (kt + 1 < 16) {
#pragma unroll
      for (int m = 0; m < 2; ++m)
        afr[(kt + 1) & 1][m] = cvt8(xraw[(kt + 1) % 3][m][0], xraw[(kt + 1) % 3][m][1]);
    }
    // (4) reload this slot's B frags for chunk kt+2.
    if (kt + 2 < 16) {
#pragma unroll
      for (int nt = 0; nt < 4; ++nt)
        bfr[kt & 1][nt] = bfrag<P>(wp, w1, 512, 0, wid * 4 + nt, 16, kt + 2, lane);
    }
    // Pin iteration boundaries: prevents full-unroll load hoisting (the
    // r1/r6 spill failure mode). Compile-time only.
    __builtin_amdgcn_sched_barrier(0);
  }

  // Hoist L2 weights + L1 bias (latency hides under the H1-epilogue VALU)
  short8 bfr2[2][8];
#pragma unroll
  for (int n = 0; n < 2; ++n)
#pragma unroll
    for (int kt = 0; kt < 8; ++kt)
      bfr2[n][kt] = bfrag<P>(wp, w2, 256, 256, wid * 2 + n, 8, kt, lane);
  float bv1[4];
#pragma unroll
  for (int n = 0; n < 4; ++n) bv1[n] = b1[wid * 64 + n * 16 + lc];

  // L1 epilogue: bias + sigmoid -> H1 (no pre-barrier needed: LDS untouched
  // so far; each wave writes only its own H1 columns).
#pragma unroll
  for (int n = 0; n < 4; ++n) {
    const int ncol = wid * 64 + n * 16;
#pragma unroll
    for (int m = 0; m < 2; ++m)
#pragma unroll
      for (int i = 0; i < 4; ++i) {
        float v = fast_sigmoid(acc[m][n][i] + bv1[n]);
        *(uint16_t*)((char*)H1 + swzoff<512>(m * 16 + lr + i, (ncol + lc) * 2)) = f2bf(v);
      }
  }
  __syncthreads();

  // ---- Layer 2: h1[32x256] -> h2[32x128]; wave cols wid*32 (2 nt), 2 mt, KT=8
  {
    f32x4 acc2[2][2];
#pragma unroll
    for (int m = 0; m < 2; ++m)
#pragma unroll
      for (int n = 0; n < 2; ++n) acc2[m][n] = (f32x4){0.f, 0.f, 0.f, 0.f};
#pragma unroll
    for (int m = 0; m < 2; ++m) {
#pragma unroll
      for (int kt = 0; kt < 8; ++kt) {
        short8 afr2 = lds_a<512>(H1, m * 16, kt * 32, lane);
        acc2[m][0] = MFMA16(afr2, bfr2[0][kt], acc2[m][0]);
        acc2[m][1] = MFMA16(afr2, bfr2[1][kt], acc2[m][1]);
      }
    }
    // Hoist L3 weights + L2 bias
    short8 bfr3[4];
#pragma unroll
    for (int kt = 0; kt < 4; ++kt)
      bfr3[kt] = bfrag<P>(wp, w3, 128, 320, wid, 4, kt, lane);
    float bv2[2];
#pragma unroll
    for (int n = 0; n < 2; ++n) bv2[n] = b2[wid * 32 + n * 16 + lc];
    __syncthreads();  // REQUIRED: last H1 read done before H2 overlays [0,8K)
#pragma unroll
    for (int n = 0; n < 2; ++n) {
      const int ncol = wid * 32 + n * 16;
#pragma unroll
      for (int m = 0; m < 2; ++m)
#pragma unroll
        for (int i = 0; i < 4; ++i) {
          float v = fast_sigmoid(acc2[m][n][i] + bv2[n]);
          *(uint16_t*)((char*)H2 + swzoff<256>(m * 16 + lr + i, (ncol + lc) * 2)) = f2bf(v);
        }
    }
    __syncthreads();

    // ---- Layer 3: h2[32x128] -> h3[32x64]; wave col-tile wid (1 nt), 2 mt, KT=4
    f32x4 acc3[2];
#pragma unroll
    for (int m = 0; m < 2; ++m) acc3[m] = (f32x4){0.f, 0.f, 0.f, 0.f};
#pragma unroll
    for (int m = 0; m < 2; ++m)
#pragma unroll
      for (int kt = 0; kt < 4; ++kt) {
        short8 afr3 = lds_a<256>(H2, m * 16, kt * 32, lane);
        acc3[m] = MFMA16(afr3, bfr3[kt], acc3[m]);
      }
    // Hoist L4 weights + L3 bias
    short8 bfr4[2];
#pragma unroll
    for (int kt = 0; kt < 2; ++kt)
      bfr4[kt] = bfrag<P>(wp, w4, 64, 336, wid & 1, 2, kt, lane);
    const float bv3 = b3[wid * 16 + lc];
    // H3 [8K,12K) disjoint from H2 [0,8K): no barrier needed before write
    {
#pragma unroll
      for (int m = 0; m < 2; ++m)
#pragma unroll
        for (int i = 0; i < 4; ++i) {
          float v = fast_sigmoid(acc3[m][i] + bv3);
          *(uint16_t*)((char*)H3 + swzoff<128>(m * 16 + lr + i, (wid * 16 + lc) * 2)) = f2bf(v);
        }
    }
    __syncthreads();

    // ---- Layer 4: h3[32x64] -> h4[32x32]; waves 2x2: rows wm*16, col wn*16, KT=2
    const int wm = wid >> 1, wn = wid & 1;
    f32x4 acc4 = (f32x4){0.f, 0.f, 0.f, 0.f};
#pragma unroll
    for (int kt = 0; kt < 2; ++kt) {
      short8 afr4 = lds_a<128>(H3, wm * 16, kt * 32, lane);
      acc4 = MFMA16(afr4, bfr4[kt], acc4);
    }
    // Hoist L5 weights + L4/L5 bias
    short8 bfr5[8];
#pragma unroll
    for (int nt = 0; nt < 8; ++nt)
      bfr5[nt] = bfrag<P>(wp, w5, 32, 340, wid * 8 + nt, 1, 0, lane);
    const float bv4 = b4[wn * 16 + lc];
    float bv5[8];
#pragma unroll
    for (int nt = 0; nt < 8; ++nt) bv5[nt] = b5[wid * 128 + nt * 16 + lc];
    // H4 [12K,14K) disjoint from H3 reads: no barrier needed before write
    {
#pragma unroll
      for (int i = 0; i < 4; ++i) {
        float v = fast_sigmoid(acc4[i] + bv4);
        *(uint16_t*)((char*)H4 + swzoff<64>(wm * 16 + lr + i, (wn * 16 + lc) * 2)) = f2bf(v);
      }
    }
    __syncthreads();

    // ---- Layer 5: h4[32x32] -> out[32x512]; wave cols wid*128 (8 nt), 2 mt, KT=1
#pragma unroll
    for (int m = 0; m < 2; ++m) {
      short8 afr5 = lds_a<64>(H4, m * 16, 0, lane);
#pragma unroll
      for (int nt = 0; nt < 8; ++nt) {
        f32x4 av = MFMA16(afr5, bfr5[nt], ((f32x4){0.f, 0.f, 0.f, 0.f}));
        const int col = wid * 128 + nt * 16 + lc;
        const bool keep = col < in_size;
#pragma unroll
        for (int i = 0; i < 4; ++i) {
          float v = keep ? (av[i] + bv5[nt]) : 0.f;
          out[(size_t)(row0 + m * 16 + lr + i) * 512 + col] = v;
        }
      }
    }
  }
}

extern "C" void kernel_launch(void* const* d_in, const int* in_sizes, int n_in,
                              void* d_out, int out_size, void* d_ws, size_t ws_size,
                              hipStream_t stream) {
  const float* x  = (const float*)d_in[0];
  const float* w1 = (const float*)d_in[1];
  const float* b1 = (const float*)d_in[2];
  const float* w2 = (const float*)d_in[3];
  const float* b2 = (const float*)d_in[4];
  const float* w3 = (const float*)d_in[5];
  const float* b3 = (const float*)d_in[6];
  const float* w4 = (const float*)d_in[7];
  const float* b4 = (const float*)d_in[8];
  const float* w5 = (const float*)d_in[9];
  const float* b5 = (const float*)d_in[10];
  float* out = (float*)d_out;

  dim3 grid(65536 / 32);
  dim3 block(256);
  const bool packed = ws_size >= (size_t)(372 * 1024);
  if (packed) {
    pack_kernel<<<372, 64, 0, stream>>>(w1, w2, w3, w4, w5, (char*)d_ws);
    mlp5_kernel<true><<<grid, block, 0, stream>>>(x, w1, b1, w2, b2, w3, b3, w4, b4,
                                                  w5, b5, (const char*)d_ws, out);
  } else {
    mlp5_kernel<false><<<grid, block, 0, stream>>>(x, w1, b1, w2, b2, w3, b3, w4, b4,
                                                   w5, b5, nullptr, out);
  }
}

// Round 9
// 73.404 us; speedup vs baseline: 1.7791x; 1.4940x over previous
//
#include <hip/hip_runtime.h>
#include <hip/hip_bf16.h>
#include <stdint.h>

typedef __attribute__((ext_vector_type(4))) float f32x4;
typedef __attribute__((ext_vector_type(4))) unsigned int u32x4;
typedef __attribute__((ext_vector_type(8))) short short8;

#define MFMA16(a, b, c) __builtin_amdgcn_mfma_f32_16x16x32_bf16((a), (b), (c), 0, 0, 0)

__device__ __forceinline__ uint16_t f2bf(float f) {
  __hip_bfloat16 h = __float2bfloat16(f);
  return __builtin_bit_cast(uint16_t, h);
}

// v_rcp_f32-based sigmoid: rcp rel-err ~1ulp << bf16 rounding of every consumer.
__device__ __forceinline__ float fast_sigmoid(float v) {
  return __builtin_amdgcn_rcpf(1.f + __expf(-v));
}

__device__ __forceinline__ short8 cvt8(f32x4 a, f32x4 b) {
  short8 r;
  r[0] = (short)f2bf(a[0]); r[1] = (short)f2bf(a[1]);
  r[2] = (short)f2bf(a[2]); r[3] = (short)f2bf(a[3]);
  r[4] = (short)f2bf(b[0]); r[5] = (short)f2bf(b[1]);
  r[6] = (short)f2bf(b[2]); r[7] = (short)f2bf(b[3]);
  return r;
}

__device__ __forceinline__ uint32_t pk2(float a, float b) {
  return (uint32_t)f2bf(a) | ((uint32_t)f2bf(b) << 16);
}

// XOR-swizzled byte offset into row-major [rows][RB bytes] LDS tile (16B slots).
template <int RB>
__device__ __forceinline__ int swzoff(int row, int bcol) {
  constexpr int SLM = (((RB / 16) < 8 ? (RB / 16) : 8)) - 1;
  return row * RB + (bcol ^ ((row & SLM) << 4));
}

// A-fragment (16x32 bf16) from swizzled bf16 LDS tile.
template <int RB>
__device__ __forceinline__ short8 lds_a(const uint16_t* buf, int row0, int k0, int lane) {
  int r = row0 + (lane & 15);
  int bcol = (k0 + ((lane >> 4) << 3)) * 2;
  u32x4 raw = *(const u32x4*)((const char*)buf + swzoff<RB>(r, bcol));
  return __builtin_bit_cast(short8, raw);
}

// Fragment from row-major fp32 M[ld] (coalesced 16-row pattern)
__device__ __forceinline__ short8 load_frag_f32(const float* M, int ld, int r0, int k0, int lane) {
  const float* p = M + (size_t)(r0 + (lane & 15)) * ld + (k0 + ((lane >> 4) << 3));
  f32x4 a = *(const f32x4*)p;
  f32x4 b = *(const f32x4*)(p + 4);
  return cvt8(a, b);
}

// Packed-path B-fragment: one coalesced 16B load from pre-packed d_ws
__device__ __forceinline__ short8 load_b_pk(const char* base, int f, int lane) {
  u32x4 raw = *(const u32x4*)(base + (((size_t)f * 64 + lane) << 4));
  return __builtin_bit_cast(short8, raw);
}

template <bool P>
__device__ __forceinline__ short8 bfrag(const char* wp, const float* W, int K,
                                        int f0, int ntg, int KT, int kt, int lane) {
  if constexpr (P) {
    return load_b_pk(wp, f0 + ntg * KT + kt, lane);
  } else {
    return load_frag_f32(W, K, ntg * 16, kt * 32, lane);
  }
}

// ---- weight pre-pack: 372 fragments x (64 lanes x 16B) = 372 KB in d_ws ----
__global__ void pack_kernel(const float* __restrict__ w1, const float* __restrict__ w2,
                            const float* __restrict__ w3, const float* __restrict__ w4,
                            const float* __restrict__ w5, char* __restrict__ ws) {
  int b = blockIdx.x, lane = threadIdx.x;
  const float* W;
  int K, f0;
  if (b < 256)      { W = w1; K = 512; f0 = 0; }
  else if (b < 320) { W = w2; K = 256; f0 = 256; }
  else if (b < 336) { W = w3; K = 128; f0 = 320; }
  else if (b < 340) { W = w4; K = 64;  f0 = 336; }
  else              { W = w5; K = 32;  f0 = 340; }
  int f = b - f0;
  int KT = K / 32;
  int nt = f / KT, kt = f % KT;
  short8 r = load_frag_f32(W, K, nt * 16, kt * 32, lane);
  *(u32x4*)(ws + (((size_t)b * 64 + lane) << 4)) = __builtin_bit_cast(u32x4, r);
}

// 32 rows/block, 256 threads, 2048 blocks.
// L1 = ONE-SHOT STAGE + FREE-RUN: the whole 32x512 x-tile is staged to a
// 32KB XOR-swizzled bf16 LDS tile with 16 perfectly-coalesced f32x4 loads per
// thread issued at kernel entry (one exposed HBM latency per block), ONE
// __syncthreads, then 16 K-chunks of pure {2 ds_read_b128 + 8 MFMA + B
// ping-pong} with ZERO barriers. This keeps r5's cooperative staging (r7/r8
// showed removing it costs more than it saves) while removing r5's 8
// barrier-gated convoy points. Bytes identical to r5.
// (256,3): VGPR cap 168; peak live regs managed ~120-150 (bfr[1] issued after
// the stage stores). Spill guard = WRITE_SIZE staying ~131MB.
template <bool P>
__global__ __launch_bounds__(256, 3) void mlp5_kernel(
    const float* __restrict__ x,
    const float* __restrict__ w1, const float* __restrict__ b1,
    const float* __restrict__ w2, const float* __restrict__ b2,
    const float* __restrict__ w3, const float* __restrict__ b3,
    const float* __restrict__ w4, const float* __restrict__ b4,
    const float* __restrict__ w5, const float* __restrict__ b5,
    const char* __restrict__ wp, float* __restrict__ out) {
  // Arena 32KB (every overlay is protected by a barrier):
  //   L1: XB [32][1024B] swizzled bf16 x-tile, [0,32K)
  //   L1 epilogue (after syncthreads): H1 [0,16K) overlays XB
  //   L2: H1 in; H2 [0,8K) out (after the barrier following last H1 read)
  //   L3: H2 in, H3 [8K,12K) out
  //   L4: H3 in, H4 [12K,14K) out
  //   L5: H4 in
  __shared__ __align__(16) char smem[32 * 1024];
  uint16_t* XB = (uint16_t*)smem;                // [32][512] bf16, RB=1024
  uint16_t* H1 = (uint16_t*)smem;                // [32][256] bf16, RB=512
  uint16_t* H2 = (uint16_t*)smem;                // [32][128] bf16, RB=256
  uint16_t* H3 = (uint16_t*)(smem + 8 * 1024);   // [32][64]  bf16, RB=128
  uint16_t* H4 = (uint16_t*)(smem + 12 * 1024);  // [32][32]  bf16, RB=64

  const int tid = threadIdx.x;
  const int lane = tid & 63;
  const int wid = tid >> 6;
  const int row0 = blockIdx.x * 32;
  const int lr = (lane >> 4) << 2;
  const int lc = lane & 15;

  // ---- L1 stage issue: 16 x f32x4, flat-coalesced (wave = 1KB contiguous).
  // Load i covers row 2i+(tid>>7), float cols (tid&127)*4..+4.
  const f32x4* xs = (const f32x4*)(x + (size_t)row0 * 512);
  f32x4 xrw[16];
#pragma unroll
  for (int i = 0; i < 16; ++i) xrw[i] = xs[i * 256 + tid];

  // B frags for chunk 0 issued early (L2-hot; lands under the stage drain).
  short8 bfr[2][4];
#pragma unroll
  for (int nt = 0; nt < 4; ++nt)
    bfr[0][nt] = bfrag<P>(wp, w1, 512, 0, wid * 4 + nt, 16, 0, lane);

  // in_size = count_nonzero(x[0])
  int in_size = 0;
#pragma unroll
  for (int j = 0; j < 8; ++j) {
    float v = x[j * 64 + lane];
    in_size += (int)__popcll(__ballot(v != 0.f));
  }

  // ---- cvt + swizzled ds_write (8B per load; XOR swz preserves 8B halves).
  // Element [r][k] lands at r*1024 + (2k ^ ((r&7)<<4)) — matches lds_a<1024>.
  const int srow = tid >> 7, scol = (tid & 127) * 8;
#pragma unroll
  for (int i = 0; i < 16; ++i) {
    uint2 w;
    w.x = pk2(xrw[i][0], xrw[i][1]);
    w.y = pk2(xrw[i][2], xrw[i][3]);
    *(uint2*)(smem + swzoff<1024>(2 * i + srow, scol)) = w;
  }
  // B frags for chunk 1 (issued post-stores: caps peak live regs ~120).
#pragma unroll
  for (int nt = 0; nt < 4; ++nt)
    bfr[1][nt] = bfrag<P>(wp, w1, 512, 0, wid * 4 + nt, 16, 1, lane);

  f32x4 acc[2][4];
#pragma unroll
  for (int m = 0; m < 2; ++m)
#pragma unroll
    for (int n = 0; n < 4; ++n) acc[m][n] = (f32x4){0.f, 0.f, 0.f, 0.f};

  __syncthreads();  // the ONLY L1 barrier: XB fully staged

  // ---- Layer 1 free-run: x[32x512] @ w1[256x512]^T -> acc, no barriers.
  // Per kt: 2 ds_read_b128 (conflict-free swizzle) + 8 MFMA; B ping-pong
  // reloaded 2 chunks ahead (L2-hot, ~200cy vs ~2 chunk-steps of cover).
#pragma unroll
  for (int kt = 0; kt < 16; ++kt) {
    short8 a0 = lds_a<1024>(XB, 0, kt * 32, lane);
    short8 a1 = lds_a<1024>(XB, 16, kt * 32, lane);
#pragma unroll
    for (int nt = 0; nt < 4; ++nt) {
      acc[0][nt] = MFMA16(a0, bfr[kt & 1][nt], acc[0][nt]);
      acc[1][nt] = MFMA16(a1, bfr[kt & 1][nt], acc[1][nt]);
    }
    if (kt + 2 < 16) {
#pragma unroll
      for (int nt = 0; nt < 4; ++nt)
        bfr[kt & 1][nt] = bfrag<P>(wp, w1, 512, 0, wid * 4 + nt, 16, kt + 2, lane);
    }
    // Pin iteration boundaries (prevents whole-loop load hoisting / spills).
    __builtin_amdgcn_sched_barrier(0);
  }

  // Hoist L2 weights + L1 bias (latency hides under barrier + epilogue VALU)
  short8 bfr2[2][8];
#pragma unroll
  for (int n = 0; n < 2; ++n)
#pragma unroll
    for (int kt = 0; kt < 8; ++kt)
      bfr2[n][kt] = bfrag<P>(wp, w2, 256, 256, wid * 2 + n, 8, kt, lane);
  float bv1[4];
#pragma unroll
  for (int n = 0; n < 4; ++n) bv1[n] = b1[wid * 64 + n * 16 + lc];

  __syncthreads();  // all XB reads done before H1 overlays [0,16K)

  // L1 epilogue: bias + sigmoid -> H1
#pragma unroll
  for (int n = 0; n < 4; ++n) {
    const int ncol = wid * 64 + n * 16;
#pragma unroll
    for (int m = 0; m < 2; ++m)
#pragma unroll
      for (int i = 0; i < 4; ++i) {
        float v = fast_sigmoid(acc[m][n][i] + bv1[n]);
        *(uint16_t*)((char*)H1 + swzoff<512>(m * 16 + lr + i, (ncol + lc) * 2)) = f2bf(v);
      }
  }
  __syncthreads();

  // ---- Layer 2: h1[32x256] -> h2[32x128]; wave cols wid*32 (2 nt), 2 mt, KT=8
  {
    f32x4 acc2[2][2];
#pragma unroll
    for (int m = 0; m < 2; ++m)
#pragma unroll
      for (int n = 0; n < 2; ++n) acc2[m][n] = (f32x4){0.f, 0.f, 0.f, 0.f};
#pragma unroll
    for (int m = 0; m < 2; ++m) {
#pragma unroll
      for (int kt = 0; kt < 8; ++kt) {
        short8 afr = lds_a<512>(H1, m * 16, kt * 32, lane);
        acc2[m][0] = MFMA16(afr, bfr2[0][kt], acc2[m][0]);
        acc2[m][1] = MFMA16(afr, bfr2[1][kt], acc2[m][1]);
      }
    }
    // Hoist L3 weights + L2 bias
    short8 bfr3[4];
#pragma unroll
    for (int kt = 0; kt < 4; ++kt)
      bfr3[kt] = bfrag<P>(wp, w3, 128, 320, wid, 4, kt, lane);
    float bv2[2];
#pragma unroll
    for (int n = 0; n < 2; ++n) bv2[n] = b2[wid * 32 + n * 16 + lc];
    __syncthreads();  // REQUIRED: last H1 read done before H2 overlays [0,8K)
#pragma unroll
    for (int n = 0; n < 2; ++n) {
      const int ncol = wid * 32 + n * 16;
#pragma unroll
      for (int m = 0; m < 2; ++m)
#pragma unroll
        for (int i = 0; i < 4; ++i) {
          float v = fast_sigmoid(acc2[m][n][i] + bv2[n]);
          *(uint16_t*)((char*)H2 + swzoff<256>(m * 16 + lr + i, (ncol + lc) * 2)) = f2bf(v);
        }
    }
    __syncthreads();

    // ---- Layer 3: h2[32x128] -> h3[32x64]; wave col-tile wid (1 nt), 2 mt, KT=4
    f32x4 acc3[2];
#pragma unroll
    for (int m = 0; m < 2; ++m) acc3[m] = (f32x4){0.f, 0.f, 0.f, 0.f};
#pragma unroll
    for (int m = 0; m < 2; ++m)
#pragma unroll
      for (int kt = 0; kt < 4; ++kt) {
        short8 afr = lds_a<256>(H2, m * 16, kt * 32, lane);
        acc3[m] = MFMA16(afr, bfr3[kt], acc3[m]);
      }
    // Hoist L4 weights + L3 bias
    short8 bfr4[2];
#pragma unroll
    for (int kt = 0; kt < 2; ++kt)
      bfr4[kt] = bfrag<P>(wp, w4, 64, 336, wid & 1, 2, kt, lane);
    const float bv3 = b3[wid * 16 + lc];
    // H3 [8K,12K) disjoint from H2 [0,8K): no barrier needed before write
    {
#pragma unroll
      for (int m = 0; m < 2; ++m)
#pragma unroll
        for (int i = 0; i < 4; ++i) {
          float v = fast_sigmoid(acc3[m][i] + bv3);
          *(uint16_t*)((char*)H3 + swzoff<128>(m * 16 + lr + i, (wid * 16 + lc) * 2)) = f2bf(v);
        }
    }
    __syncthreads();

    // ---- Layer 4: h3[32x64] -> h4[32x32]; waves 2x2: rows wm*16, col wn*16, KT=2
    const int wm = wid >> 1, wn = wid & 1;
    f32x4 acc4 = (f32x4){0.f, 0.f, 0.f, 0.f};
#pragma unroll
    for (int kt = 0; kt < 2; ++kt) {
      short8 afr = lds_a<128>(H3, wm * 16, kt * 32, lane);
      acc4 = MFMA16(afr, bfr4[kt], acc4);
    }
    // Hoist L5 weights + L4/L5 bias
    short8 bfr5[8];
#pragma unroll
    for (int nt = 0; nt < 8; ++nt)
      bfr5[nt] = bfrag<P>(wp, w5, 32, 340, wid * 8 + nt, 1, 0, lane);
    const float bv4 = b4[wn * 16 + lc];
    float bv5[8];
#pragma unroll
    for (int nt = 0; nt < 8; ++nt) bv5[nt] = b5[wid * 128 + nt * 16 + lc];
    // H4 [12K,14K) disjoint from H3 reads: no barrier needed before write
    {
#pragma unroll
      for (int i = 0; i < 4; ++i) {
        float v = fast_sigmoid(acc4[i] + bv4);
        *(uint16_t*)((char*)H4 + swzoff<64>(wm * 16 + lr + i, (wn * 16 + lc) * 2)) = f2bf(v);
      }
    }
    __syncthreads();

    // ---- Layer 5: h4[32x32] -> out[32x512]; wave cols wid*128 (8 nt), 2 mt, KT=1
#pragma unroll
    for (int m = 0; m < 2; ++m) {
      short8 afr = lds_a<64>(H4, m * 16, 0, lane);
#pragma unroll
      for (int nt = 0; nt < 8; ++nt) {
        f32x4 av = MFMA16(afr, bfr5[nt], ((f32x4){0.f, 0.f, 0.f, 0.f}));
        const int col = wid * 128 + nt * 16 + lc;
        const bool keep = col < in_size;
#pragma unroll
        for (int i = 0; i < 4; ++i) {
          float v = keep ? (av[i] + bv5[nt]) : 0.f;
          out[(size_t)(row0 + m * 16 + lr + i) * 512 + col] = v;
        }
      }
    }
  }
}

extern "C" void kernel_launch(void* const* d_in, const int* in_sizes, int n_in,
                              void* d_out, int out_size, void* d_ws, size_t ws_size,
                              hipStream_t stream) {
  const float* x  = (const float*)d_in[0];
  const float* w1 = (const float*)d_in[1];
  const float* b1 = (const float*)d_in[2];
  const float* w2 = (const float*)d_in[3];
  const float* b2 = (const float*)d_in[4];
  const float* w3 = (const float*)d_in[5];
  const float* b3 = (const float*)d_in[6];
  const float* w4 = (const float*)d_in[7];
  const float* b4 = (const float*)d_in[8];
  const float* w5 = (const float*)d_in[9];
  const float* b5 = (const float*)d_in[10];
  float* out = (float*)d_out;

  dim3 grid(65536 / 32);
  dim3 block(256);
  const bool packed = ws_size >= (size_t)(372 * 1024);
  if (packed) {
    pack_kernel<<<372, 64, 0, stream>>>(w1, w2, w3, w4, w5, (char*)d_ws);
    mlp5_kernel<true><<<grid, block, 0, stream>>>(x, w1, b1, w2, b2, w3, b3, w4, b4,
                                                  w5, b5, (const char*)d_ws, out);
  } else {
    mlp5_kernel<false><<<grid, block, 0, stream>>>(x, w1, b1, w2, b2, w3, b3, w4, b4,
                                                   w5, b5, nullptr, out);
  }
}